// Round 5
// baseline (392.548 us; speedup 1.0000x reference)
//
#include <hip/hip_runtime.h>
#include <hip/hip_bf16.h>

typedef __attribute__((ext_vector_type(8))) short short8;
typedef __attribute__((ext_vector_type(4))) float f32x4;
typedef __attribute__((ext_vector_type(4))) unsigned int u32x4;

static __device__ __forceinline__ unsigned int cvt_pk_bf16(float lo, float hi) {
    unsigned int r;
    asm("v_cvt_pk_bf16_f32 %0, %1, %2" : "=v"(r) : "v"(lo), "v"(hi));
    return r;
}

// ---------------------------------------------------------------------------
// k_wcvt: swizzled bf16 copy of lc_w.
// Wbf[i][c*32 + cu*8 + e] = bf16(W[i][c*32 + (cu ^ ((i>>1)&3))*8 + e])
// so that linear global_load_lds staging + XOR'd ds_read gives conflict-free
// LDS reads (pre-swizzled-source pattern, rule 21).
// ---------------------------------------------------------------------------
__global__ __launch_bounds__(256) void k_wcvt(const float* __restrict__ W,
                                              unsigned short* __restrict__ Wbf) {
    long t0 = (long)blockIdx.x * 256 + threadIdx.x;
    for (long u = t0; u < 2097152L; u += 524288L) {   // 2M 8-elem units
        long i = u >> 13;                  // row (8192 units/row)
        int uu = (int)(u & 8191);
        int c = uu >> 2, cu = uu & 3;
        int s = (int)((i >> 1) & 3);
        const float* src = W + i * 65536 + c * 32 + (cu ^ s) * 8;
        f32x4 a = *(const f32x4*)src;
        f32x4 b = *(const f32x4*)(src + 4);
        u32x4 q;
        q.x = cvt_pk_bf16(a.x, a.y); q.y = cvt_pk_bf16(a.z, a.w);
        q.z = cvt_pk_bf16(b.x, b.y); q.w = cvt_pk_bf16(b.z, b.w);
        *(u32x4*)(Wbf + u * 8) = q;
    }
}

// ---------------------------------------------------------------------------
// k_pre: T[b,j,k] (4 j-rows/block) + xT[d][m] = x[m][d] + w1T[d][i] = w1[i][d]
// grid 256, 256 threads
// ---------------------------------------------------------------------------
__global__ __launch_bounds__(256) void k_pre(const float* __restrict__ x,
                                             const float* __restrict__ w1,
                                             float* __restrict__ T,
                                             float* __restrict__ xT,
                                             float* __restrict__ w1T) {
    int bid = blockIdx.x, t = threadIdx.x;
    w1T[(long)bid * 256 + t] = w1[(long)t * 256 + bid];

    // xT slice: rows m = bid*4 .. +4
    {
        f32x4 v;
        v.x = x[((long)bid * 4 + 0) * 256 + t];
        v.y = x[((long)bid * 4 + 1) * 256 + t];
        v.z = x[((long)bid * 4 + 2) * 256 + t];
        v.w = x[((long)bid * 4 + 3) * 256 + t];
        *(f32x4*)&xT[(long)t * 1024 + bid * 4] = v;
    }

    int b = bid >> 6;
    int j4 = (bid & 63) * 4;
    const float* xb = x + (long)b * 65536;
    float ac0 = 0.f, ac1 = 0.f, ac2 = 0.f, ac3 = 0.f;
    #pragma unroll 8
    for (int qq = 0; qq < 256; ++qq) {
        const float* row = xb + (long)qq * 256;
        float xk = row[t];
        float xk2 = xk * xk;
        f32x4 aj = *(const f32x4*)(row + j4);
        ac0 = fmaf(aj.x * aj.x, xk2, ac0);
        ac1 = fmaf(aj.y * aj.y, xk2, ac1);
        ac2 = fmaf(aj.z * aj.z, xk2, ac2);
        ac3 = fmaf(aj.w * aj.w, xk2, ac3);
    }
    long base = (long)b * 65536 + (long)j4 * 256 + t;
    T[base +   0] = (j4     == t) ? 0.f : 1.f / (1.f - ac0);
    T[base + 256] = (j4 + 1 == t) ? 0.f : 1.f / (1.f - ac1);
    T[base + 512] = (j4 + 2 == t) ? 0.f : 1.f / (1.f - ac2);
    T[base + 768] = (j4 + 3 == t) ? 0.f : 1.f / (1.f - ac3);
}

// ---------------------------------------------------------------------------
// k_gemm: partials[sp][m][i] = sum_{jk in 1K chunk} (x_j x_k T[jk]) * W[i,jk]
//   A: generated per-lane in REGISTERS (no LDS) from xT + T; exact MFMA layout
//   B: swizzled Wbf staged via global_load_lds into dbuf linear LDS
// BM=128 BN=128 BK=32, 4 waves (2x2), SPLIT=64, grid 1024 (3 blocks/CU).
// bid = mt*128 + nt*64 + sp  ->  bid%8 = sp%8: W-chunk sharers co-XCD.
// ---------------------------------------------------------------------------
__global__ __launch_bounds__(256, 3) void k_gemm(const float* __restrict__ xT,
                                                 const unsigned short* __restrict__ Wbf,
                                                 const float* __restrict__ T,
                                                 float* __restrict__ partials) {
    __shared__ unsigned short Bs[2][128][32];   // 16 KB, linear (gload_lds dest)

    const int bid = blockIdx.x;
    const int mt = bid >> 7;           // 0..7
    const int nt = (bid >> 6) & 1;     // 0..1
    const int sp = bid & 63;           // 0..63
    const int tid = threadIdx.x;
    const int lane = tid & 63;
    const int l15 = lane & 15;
    const int cu = lane >> 4;          // k-unit of this lane's fragment
    const int wid = tid >> 6;
    const int wm = wid >> 1, wn = wid & 1;
    const int b = mt >> 1;
    const int xu = cu ^ ((l15 >> 1) & 3);   // swizzled B-read unit

    // B staging: wave wid covers rows wid*32..+32 (2 x 16-row gload_lds)
    const unsigned short* Bsrc0 = Wbf + (long)(nt * 128 + wid * 32 + (lane >> 2)) * 65536
                                      + (long)sp * 1024 + (lane & 3) * 8;
    const unsigned short* Bsrc1 = Bsrc0 + 16L * 65536;

    const int rbase = mt * 128 + wm * 64 + l15;   // + mf*16 per fragment row

    // all 4 j-values of this chunk, all 4 mf rows: preload once
    float xj[4][4];
    #pragma unroll
    for (int mf = 0; mf < 4; ++mf)
        #pragma unroll
        for (int jj = 0; jj < 4; ++jj)
            xj[mf][jj] = xT[(long)(sp * 4 + jj) * 1024 + rbase + mf * 16];

    const float* Trow = T + (long)b * 65536 + (long)(sp * 4) * 256 + cu * 8;

    f32x4 acc[4][4];
    #pragma unroll
    for (int a = 0; a < 4; ++a)
        #pragma unroll
        for (int c = 0; c < 4; ++c) acc[a][c] = (f32x4){0.f, 0.f, 0.f, 0.f};

    float xk[4][8];          // x[row_mf][kw*32 + cu*8 + e] for current kw
    f32x4 tA, tB;            // T for the CURRENT step (prefetched one ahead)

    // ---- prologue: stage step 0, T(0), xk(kw=0) ----
    __builtin_amdgcn_global_load_lds(
        (const __attribute__((address_space(1))) unsigned int*)Bsrc0,
        (__attribute__((address_space(3))) unsigned int*)&Bs[0][wid * 32][0], 16, 0, 0);
    __builtin_amdgcn_global_load_lds(
        (const __attribute__((address_space(1))) unsigned int*)Bsrc1,
        (__attribute__((address_space(3))) unsigned int*)&Bs[0][wid * 32 + 16][0], 16, 0, 0);
    tA = *(const f32x4*)(Trow + 0);
    tB = *(const f32x4*)(Trow + 4);
    #pragma unroll
    for (int mf = 0; mf < 4; ++mf)
        #pragma unroll
        for (int e = 0; e < 8; ++e)
            xk[mf][e] = xT[(long)(cu * 8 + e) * 1024 + rbase + mf * 16];
    __syncthreads();

    #pragma unroll 1
    for (int kw = 0; kw < 8; ++kw) {
        #pragma unroll
        for (int jj = 0; jj < 4; ++jj) {             // kt = kw*4 + jj
            const int buf = jj & 1;
            const bool last = (jj == 3) && (kw == 7);
            const long noff = (jj == 3) ? (long)(kw + 1) * 32
                                        : (long)(jj + 1) * 256 + (long)kw * 32;
            // 1. stage next-step B
            if (!last) {
                __builtin_amdgcn_global_load_lds(
                    (const __attribute__((address_space(1))) unsigned int*)(Bsrc0 + noff),
                    (__attribute__((address_space(3))) unsigned int*)&Bs[buf ^ 1][wid * 32][0], 16, 0, 0);
                __builtin_amdgcn_global_load_lds(
                    (const __attribute__((address_space(1))) unsigned int*)(Bsrc1 + noff),
                    (__attribute__((address_space(3))) unsigned int*)&Bs[buf ^ 1][wid * 32 + 16][0], 16, 0, 0);
            }
            // 2. roll T: consume current, prefetch next
            f32x4 ta = tA, tb = tB;
            if (!last) {
                tA = *(const f32x4*)(Trow + noff);
                tB = *(const f32x4*)(Trow + noff + 4);
            }
            // 3. B fragments (swizzled read) + in-reg A fragments + 16 MFMA
            short8 bfv[4];
            #pragma unroll
            for (int nf = 0; nf < 4; ++nf)
                bfv[nf] = *(const short8*)((const char*)(&Bs[buf][0][0])
                            + (wn * 64 + nf * 16 + l15) * 64 + xu * 16);
            #pragma unroll
            for (int mf = 0; mf < 4; ++mf) {
                const float xje = xj[mf][jj];
                union { unsigned int u[4]; short8 s; } A;
                A.u[0] = cvt_pk_bf16(xje * xk[mf][0] * ta.x, xje * xk[mf][1] * ta.y);
                A.u[1] = cvt_pk_bf16(xje * xk[mf][2] * ta.z, xje * xk[mf][3] * ta.w);
                A.u[2] = cvt_pk_bf16(xje * xk[mf][4] * tb.x, xje * xk[mf][5] * tb.y);
                A.u[3] = cvt_pk_bf16(xje * xk[mf][6] * tb.z, xje * xk[mf][7] * tb.w);
                #pragma unroll
                for (int nf = 0; nf < 4; ++nf)
                    acc[mf][nf] = __builtin_amdgcn_mfma_f32_16x16x32_bf16(
                        A.s, bfv[nf], acc[mf][nf], 0, 0, 0);
            }
            // 4. reload xk for next k-window (once per 4 steps)
            if (jj == 3 && kw < 7) {
                #pragma unroll
                for (int mf = 0; mf < 4; ++mf)
                    #pragma unroll
                    for (int e = 0; e < 8; ++e)
                        xk[mf][e] = xT[(long)((kw + 1) * 32 + cu * 8 + e) * 1024 + rbase + mf * 16];
            }
            __syncthreads();
        }
    }

    // epilogue: C/D layout col = lane&15, row = (lane>>4)*4 + reg
    float* Pp = partials + (long)sp * 262144;
    #pragma unroll
    for (int mf = 0; mf < 4; ++mf) {
        int rowb = mt * 128 + wm * 64 + mf * 16 + (lane >> 4) * 4;
        #pragma unroll
        for (int nf = 0; nf < 4; ++nf) {
            int col = nt * 128 + wn * 64 + nf * 16 + l15;
            #pragma unroll
            for (int rr = 0; rr < 4; ++rr)
                Pp[(long)(rowb + rr) * 256 + col] = acc[mf][nf][rr];
        }
    }
}

// ---------------------------------------------------------------------------
// k_finish: y = bias + sum_sp partials + x@w1T; BatchNorm over (b,o) per q;
// one block per channel q (grid 256).
// ---------------------------------------------------------------------------
__global__ __launch_bounds__(256) void k_finish(const float* __restrict__ partials,
                                                const float* __restrict__ x,
                                                const float* __restrict__ w1T,
                                                const float* __restrict__ bias,
                                                const float* __restrict__ gamma,
                                                const float* __restrict__ beta,
                                                float* __restrict__ out) {
    int q = blockIdx.x;
    int o = threadIdx.x;
    __shared__ float xs[4][256];
    #pragma unroll
    for (int bb = 0; bb < 4; ++bb)
        xs[bb][o] = x[((long)bb * 256 + q) * 256 + o];
    __syncthreads();

    float bs = bias[o];
    float a0 = bs, a1 = bs, a2 = bs, a3 = bs;
    #pragma unroll 4
    for (int spi = 0; spi < 64; ++spi) {
        const float* P = partials + ((long)spi * 1024 + q) * 256 + o;
        a0 += P[0];
        a1 += P[65536];
        a2 += P[131072];
        a3 += P[196608];
    }
    #pragma unroll 8
    for (int d = 0; d < 256; ++d) {
        float wv = w1T[(long)d * 256 + o];
        a0 = fmaf(xs[0][d], wv, a0);
        a1 = fmaf(xs[1][d], wv, a1);
        a2 = fmaf(xs[2][d], wv, a2);
        a3 = fmaf(xs[3][d], wv, a3);
    }
    // BatchNorm stats over the 1024 values of channel q
    float s = a0 + a1 + a2 + a3;
    float sq = a0 * a0 + a1 * a1 + a2 * a2 + a3 * a3;
    #pragma unroll
    for (int off = 32; off > 0; off >>= 1) {
        s  += __shfl_down(s, off, 64);
        sq += __shfl_down(sq, off, 64);
    }
    __shared__ float rs[4], rq[4];
    int lane = o & 63, wv_ = o >> 6;
    if (lane == 0) { rs[wv_] = s; rq[wv_] = sq; }
    __syncthreads();
    float ts = rs[0] + rs[1] + rs[2] + rs[3];
    float tq = rq[0] + rq[1] + rq[2] + rq[3];
    float mean = ts * (1.f / 1024.f);
    float var = tq * (1.f / 1024.f) - mean * mean;   // biased, matches ref
    float rstd = rsqrtf(var + 1e-5f);
    float g = gamma[q], be = beta[q];
    out[((long)0 * 256 + q) * 256 + o] = fmaf((a0 - mean) * rstd, g, be);
    out[((long)1 * 256 + q) * 256 + o] = fmaf((a1 - mean) * rstd, g, be);
    out[((long)2 * 256 + q) * 256 + o] = fmaf((a2 - mean) * rstd, g, be);
    out[((long)3 * 256 + q) * 256 + o] = fmaf((a3 - mean) * rstd, g, be);
}

// ---------------------------------------------------------------------------
extern "C" void kernel_launch(void* const* d_in, const int* in_sizes, int n_in,
                              void* d_out, int out_size, void* d_ws, size_t ws_size,
                              hipStream_t stream) {
    const float* x     = (const float*)d_in[0];
    const float* lc_w  = (const float*)d_in[1];
    const float* w1    = (const float*)d_in[2];
    const float* bias  = (const float*)d_in[3];
    const float* gamma = (const float*)d_in[4];
    const float* beta  = (const float*)d_in[5];
    float* out = (float*)d_out;

    char* ws = (char*)d_ws;
    size_t o_T    = 0;                     // 1 MB
    size_t o_xT   = o_T + 1048576;         // 1 MB
    size_t o_w1T  = o_xT + 1048576;        // 256 KB
    size_t o_Wbf  = o_w1T + 262144;        // 32 MB
    size_t o_part = o_Wbf + 33554432;      // 67.1 MB  (total ~101.5 MB)

    float*          T        = (float*)(ws + o_T);
    float*          xT       = (float*)(ws + o_xT);
    float*          w1T      = (float*)(ws + o_w1T);
    unsigned short* Wbf      = (unsigned short*)(ws + o_Wbf);
    float*          partials = (float*)(ws + o_part);

    k_wcvt  <<<2048, 256, 0, stream>>>(lc_w, Wbf);
    k_pre   <<<256,  256, 0, stream>>>(x, w1, T, xT, w1T);
    k_gemm  <<<1024, 256, 0, stream>>>(xT, Wbf, T, partials);
    k_finish<<<256,  256, 0, stream>>>(partials, x, w1T, bias, gamma, beta, out);
}

// Round 6
// 204.772 us; speedup vs baseline: 1.9170x; 1.9170x over previous
//
#include <hip/hip_runtime.h>
#include <hip/hip_bf16.h>

typedef __attribute__((ext_vector_type(8))) short short8;
typedef __attribute__((ext_vector_type(4))) float f32x4;
typedef __attribute__((ext_vector_type(4))) unsigned int u32x4;

#define LDP 40   // padded A rows (80 B): 2-way-only conflicts on As reads

static __device__ __forceinline__ unsigned int cvt_pk_bf16(float lo, float hi) {
    unsigned int r;
    asm("v_cvt_pk_bf16_f32 %0, %1, %2" : "=v"(r) : "v"(lo), "v"(hi));
    return r;
}

// ---------------------------------------------------------------------------
// k_wcvt: swizzled bf16 copies of lc_w and w1.
// Within every 32-elem group: unit cu (8 elems) stores source unit cu^((row>>1)&3).
// Linear gload_lds staging + XOR'd ds_read then gives ~2-way (free) conflicts.
// Validated numerically + conflicts==0 in round 5.
// ---------------------------------------------------------------------------
__global__ __launch_bounds__(256) void k_wcvt(const float* __restrict__ W,
                                              const float* __restrict__ w1,
                                              unsigned short* __restrict__ Wbf,
                                              unsigned short* __restrict__ w1bf) {
    long t0 = (long)blockIdx.x * 256 + threadIdx.x;
    for (long u = t0; u < 2097152L; u += 524288L) {   // lc_w: 2M 8-elem units
        long i = u >> 13;                  // row (8192 units per 65536-elem row)
        int uu = (int)(u & 8191);
        int c = uu >> 2, cu = uu & 3;
        int s = (int)((i >> 1) & 3);
        const float* src = W + i * 65536 + c * 32 + (cu ^ s) * 8;
        f32x4 a = *(const f32x4*)src;
        f32x4 b = *(const f32x4*)(src + 4);
        u32x4 q;
        q.x = cvt_pk_bf16(a.x, a.y); q.y = cvt_pk_bf16(a.z, a.w);
        q.z = cvt_pk_bf16(b.x, b.y); q.w = cvt_pk_bf16(b.z, b.w);
        *(u32x4*)(Wbf + u * 8) = q;
    }
    if (t0 < 8192) {                       // w1: 8K units (256x256)
        long u = t0;
        long i = u >> 5;                   // row (32 units per 256-elem row)
        int uu = (int)(u & 31);
        int c = uu >> 2, cu = uu & 3;
        int s = (int)((i >> 1) & 3);
        const float* src = w1 + i * 256 + c * 32 + (cu ^ s) * 8;
        f32x4 a = *(const f32x4*)src;
        f32x4 b = *(const f32x4*)(src + 4);
        u32x4 q;
        q.x = cvt_pk_bf16(a.x, a.y); q.y = cvt_pk_bf16(a.z, a.w);
        q.z = cvt_pk_bf16(b.x, b.y); q.w = cvt_pk_bf16(b.z, b.w);
        *(u32x4*)(w1bf + u * 8) = q;
    }
}

// ---------------------------------------------------------------------------
// k_pre: T[b,j,k] = (j==k) ? 0 : 1/(1 - sum_q x_j^2 x_k^2)   (4 j-rows/block)
// ---------------------------------------------------------------------------
__global__ __launch_bounds__(256) void k_pre(const float* __restrict__ x,
                                             float* __restrict__ T) {
    int bid = blockIdx.x, t = threadIdx.x;
    int b = bid >> 6;
    int j4 = (bid & 63) * 4;
    const float* xb = x + (long)b * 65536;
    float ac0 = 0.f, ac1 = 0.f, ac2 = 0.f, ac3 = 0.f;
    #pragma unroll 8
    for (int qq = 0; qq < 256; ++qq) {
        const float* row = xb + (long)qq * 256;
        float xk = row[t];
        float xk2 = xk * xk;
        f32x4 aj = *(const f32x4*)(row + j4);
        ac0 = fmaf(aj.x * aj.x, xk2, ac0);
        ac1 = fmaf(aj.y * aj.y, xk2, ac1);
        ac2 = fmaf(aj.z * aj.z, xk2, ac2);
        ac3 = fmaf(aj.w * aj.w, xk2, ac3);
    }
    long base = (long)b * 65536 + (long)j4 * 256 + t;
    T[base +   0] = (j4     == t) ? 0.f : 1.f / (1.f - ac0);
    T[base + 256] = (j4 + 1 == t) ? 0.f : 1.f / (1.f - ac1);
    T[base + 512] = (j4 + 2 == t) ? 0.f : 1.f / (1.f - ac2);
    T[base + 768] = (j4 + 3 == t) ? 0.f : 1.f / (1.f - ac3);
}

// ---------------------------------------------------------------------------
// k_gemm: partials[sp][m][i] = sum_{jk chunk} (x_j x_k T[jk]) * W[i,jk]
//   B = swizzled bf16 W via global_load_lds into linear dbuf LDS, XOR'd read
//   A = computed in-register from x,T (broadcast/cheap loads) -> padded LDS
//   sp<8 blocks append one K-step of the base linear (A=bf16(x), B=w1bf)
// grid 512 (ALL blocks resident: 2/CU — this is what keeps FETCH at 23 MB);
// bid = mt*64 + nt*32 + sp.
// ---------------------------------------------------------------------------
__global__ __launch_bounds__(256, 3) void k_gemm(const float* __restrict__ x,
                                                 const unsigned short* __restrict__ Wbf,
                                                 const unsigned short* __restrict__ w1bf,
                                                 const float* __restrict__ T,
                                                 float* __restrict__ partials) {
    __shared__ unsigned short As[2][128][LDP];   // 20 KB
    __shared__ unsigned short Bs[2][128][32];    // 16 KB, linear (gload_lds dest)

    const int bid = blockIdx.x;
    const int mt = bid >> 6;            // 0..7
    const int nt = (bid >> 5) & 1;      // 0..1
    const int sp = bid & 31;            // 0..31
    const int tid = threadIdx.x;
    const int lane = tid & 63;
    const int l15 = lane & 15;
    const int cu = lane >> 4;           // k-unit of this lane's fragment
    const int xu = cu ^ ((l15 >> 1) & 3);  // swizzled B-read unit (s depends only on l15)
    const int wid = tid >> 6;
    const int wm = wid >> 1, wn = wid & 1;
    const int b = mt >> 1;

    // A staging role: one row, 16 cols per thread
    const int r = tid >> 1;
    const int ch = (tid & 1) * 16;

    const float* xrow = x + (long)(mt * 128 + r) * 256;
    const float* Trow = T + (long)b * 65536 + (long)(sp * 8) * 256 + ch;

    // B staging: wave wid covers rows wid*32..+32 (2 gload_lds, 16 rows each)
    const unsigned short* Bsrc0 = Wbf + (long)(nt * 128 + wid * 32 + (lane >> 2)) * 65536
                                      + (long)sp * 2048 + (lane & 3) * 8;
    const unsigned short* Bsrc1 = Bsrc0 + 16L * 65536;

    // the 8 j-values of this chunk for this thread's A row
    f32x4 xjA = *(const f32x4*)(xrow + sp * 8);
    f32x4 xjB = *(const f32x4*)(xrow + sp * 8 + 4);
    const float xj8[8] = {xjA.x, xjA.y, xjA.z, xjA.w, xjB.x, xjB.y, xjB.z, xjB.w};

    f32x4 acc[4][4];
    #pragma unroll
    for (int a = 0; a < 4; ++a)
        #pragma unroll
        for (int c = 0; c < 4; ++c) acc[a][c] = (f32x4){0.f, 0.f, 0.f, 0.f};

    f32x4 xw0, xw1, xw2, xw3;   // current k-window x (this thread's 16 cols)

    // ---- prologue: stage step 0 into buf 0 ----
    {
        __builtin_amdgcn_global_load_lds(
            (const __attribute__((address_space(1))) unsigned int*)Bsrc0,
            (__attribute__((address_space(3))) unsigned int*)&Bs[0][wid * 32][0], 16, 0, 0);
        __builtin_amdgcn_global_load_lds(
            (const __attribute__((address_space(1))) unsigned int*)Bsrc1,
            (__attribute__((address_space(3))) unsigned int*)&Bs[0][wid * 32 + 16][0], 16, 0, 0);
        xw0 = *(const f32x4*)(xrow + ch + 0);
        xw1 = *(const f32x4*)(xrow + ch + 4);
        xw2 = *(const f32x4*)(xrow + ch + 8);
        xw3 = *(const f32x4*)(xrow + ch + 12);
        f32x4 t0 = *(const f32x4*)(Trow + 0);
        f32x4 t1 = *(const f32x4*)(Trow + 4);
        f32x4 t2 = *(const f32x4*)(Trow + 8);
        f32x4 t3 = *(const f32x4*)(Trow + 12);
        const float xj = xj8[0];
        u32x4 qa, qb;
        qa.x = cvt_pk_bf16(xj * xw0.x * t0.x, xj * xw0.y * t0.y);
        qa.y = cvt_pk_bf16(xj * xw0.z * t0.z, xj * xw0.w * t0.w);
        qa.z = cvt_pk_bf16(xj * xw1.x * t1.x, xj * xw1.y * t1.y);
        qa.w = cvt_pk_bf16(xj * xw1.z * t1.z, xj * xw1.w * t1.w);
        qb.x = cvt_pk_bf16(xj * xw2.x * t2.x, xj * xw2.y * t2.y);
        qb.y = cvt_pk_bf16(xj * xw2.z * t2.z, xj * xw2.w * t2.w);
        qb.z = cvt_pk_bf16(xj * xw3.x * t3.x, xj * xw3.y * t3.y);
        qb.w = cvt_pk_bf16(xj * xw3.z * t3.z, xj * xw3.w * t3.w);
        *(u32x4*)&As[0][r][ch]     = qa;
        *(u32x4*)&As[0][r][ch + 8] = qb;
    }
    __syncthreads();

    #pragma unroll 1
    for (int kw = 0; kw < 8; ++kw) {
        #pragma unroll
        for (int jj = 0; jj < 8; ++jj) {
            const int buf = jj & 1;
            const int nbuf = buf ^ 1;
            const int njj = (jj + 1) & 7;
            const int nkw = (jj == 7) ? kw + 1 : kw;
            const bool last = (jj == 7) && (kw == 7);

            // ---- 1. issue next-step B (gload_lds) + T/x loads ----
            f32x4 t0, t1, t2, t3;
            f32x4 nx0 = xw0, nx1 = xw1, nx2 = xw2, nx3 = xw3;
            if (!last) {
                const long noff = (long)njj * 256 + (long)nkw * 32;   // bf16 elems
                __builtin_amdgcn_global_load_lds(
                    (const __attribute__((address_space(1))) unsigned int*)(Bsrc0 + noff),
                    (__attribute__((address_space(3))) unsigned int*)&Bs[nbuf][wid * 32][0], 16, 0, 0);
                __builtin_amdgcn_global_load_lds(
                    (const __attribute__((address_space(1))) unsigned int*)(Bsrc1 + noff),
                    (__attribute__((address_space(3))) unsigned int*)&Bs[nbuf][wid * 32 + 16][0], 16, 0, 0);
                t0 = *(const f32x4*)(Trow + noff + 0);
                t1 = *(const f32x4*)(Trow + noff + 4);
                t2 = *(const f32x4*)(Trow + noff + 8);
                t3 = *(const f32x4*)(Trow + noff + 12);
                if (jj == 7) {
                    const long xo = (long)(kw + 1) * 32;
                    nx0 = *(const f32x4*)(xrow + xo + ch + 0);
                    nx1 = *(const f32x4*)(xrow + xo + ch + 4);
                    nx2 = *(const f32x4*)(xrow + xo + ch + 8);
                    nx3 = *(const f32x4*)(xrow + xo + ch + 12);
                }
            }

            // ---- 2. fragments + 16 MFMA from buf (B read XOR-swizzled) ----
            short8 af[4], bfv[4];
            #pragma unroll
            for (int mf = 0; mf < 4; ++mf)
                af[mf] = *(const short8*)&As[buf][wm * 64 + mf * 16 + l15][cu * 8];
            #pragma unroll
            for (int nf = 0; nf < 4; ++nf)
                bfv[nf] = *(const short8*)((const char*)(&Bs[buf][0][0])
                            + (wn * 64 + nf * 16 + l15) * 64 + xu * 16);
            #pragma unroll
            for (int mf = 0; mf < 4; ++mf)
                #pragma unroll
                for (int nf = 0; nf < 4; ++nf)
                    acc[mf][nf] = __builtin_amdgcn_mfma_f32_16x16x32_bf16(
                        af[mf], bfv[nf], acc[mf][nf], 0, 0, 0);

            // ---- 3. compute + write next A tile ----
            if (!last) {
                const float xjn = xj8[njj];
                u32x4 qa, qb;
                qa.x = cvt_pk_bf16(xjn * nx0.x * t0.x, xjn * nx0.y * t0.y);
                qa.y = cvt_pk_bf16(xjn * nx0.z * t0.z, xjn * nx0.w * t0.w);
                qa.z = cvt_pk_bf16(xjn * nx1.x * t1.x, xjn * nx1.y * t1.y);
                qa.w = cvt_pk_bf16(xjn * nx1.z * t1.z, xjn * nx1.w * t1.w);
                qb.x = cvt_pk_bf16(xjn * nx2.x * t2.x, xjn * nx2.y * t2.y);
                qb.y = cvt_pk_bf16(xjn * nx2.z * t2.z, xjn * nx2.w * t2.w);
                qb.z = cvt_pk_bf16(xjn * nx3.x * t3.x, xjn * nx3.y * t3.y);
                qb.w = cvt_pk_bf16(xjn * nx3.z * t3.z, xjn * nx3.w * t3.w);
                *(u32x4*)&As[nbuf][r][ch]     = qa;
                *(u32x4*)&As[nbuf][r][ch + 8] = qb;
            }
            __syncthreads();
            if (jj == 7) { xw0 = nx0; xw1 = nx1; xw2 = nx2; xw3 = nx3; }
        }
    }

    // ---- base-linear fold: sp<8 blocks do one extra K-step over w1 ----
    if (sp < 8) {
        const unsigned short* W1s = w1bf + (long)(nt * 128 + wid * 32 + (lane >> 2)) * 256
                                        + sp * 32 + (lane & 3) * 8;
        __builtin_amdgcn_global_load_lds(
            (const __attribute__((address_space(1))) unsigned int*)W1s,
            (__attribute__((address_space(3))) unsigned int*)&Bs[0][wid * 32][0], 16, 0, 0);
        __builtin_amdgcn_global_load_lds(
            (const __attribute__((address_space(1))) unsigned int*)(W1s + 16L * 256),
            (__attribute__((address_space(3))) unsigned int*)&Bs[0][wid * 32 + 16][0], 16, 0, 0);
        f32x4 a0 = *(const f32x4*)(xrow + sp * 32 + ch + 0);
        f32x4 a1 = *(const f32x4*)(xrow + sp * 32 + ch + 4);
        f32x4 a2 = *(const f32x4*)(xrow + sp * 32 + ch + 8);
        f32x4 a3 = *(const f32x4*)(xrow + sp * 32 + ch + 12);
        u32x4 qa, qb;
        qa.x = cvt_pk_bf16(a0.x, a0.y); qa.y = cvt_pk_bf16(a0.z, a0.w);
        qa.z = cvt_pk_bf16(a1.x, a1.y); qa.w = cvt_pk_bf16(a1.z, a1.w);
        qb.x = cvt_pk_bf16(a2.x, a2.y); qb.y = cvt_pk_bf16(a2.z, a2.w);
        qb.z = cvt_pk_bf16(a3.x, a3.y); qb.w = cvt_pk_bf16(a3.z, a3.w);
        *(u32x4*)&As[0][r][ch]     = qa;
        *(u32x4*)&As[0][r][ch + 8] = qb;
        __syncthreads();
        short8 af[4], bfv[4];
        #pragma unroll
        for (int mf = 0; mf < 4; ++mf)
            af[mf] = *(const short8*)&As[0][wm * 64 + mf * 16 + l15][cu * 8];
        #pragma unroll
        for (int nf = 0; nf < 4; ++nf)
            bfv[nf] = *(const short8*)((const char*)(&Bs[0][0][0])
                        + (wn * 64 + nf * 16 + l15) * 64 + xu * 16);
        #pragma unroll
        for (int mf = 0; mf < 4; ++mf)
            #pragma unroll
            for (int nf = 0; nf < 4; ++nf)
                acc[mf][nf] = __builtin_amdgcn_mfma_f32_16x16x32_bf16(
                    af[mf], bfv[nf], acc[mf][nf], 0, 0, 0);
    }

    // epilogue: C/D layout col = lane&15, row = (lane>>4)*4 + reg
    float* Pp = partials + (long)sp * 262144;
    #pragma unroll
    for (int mf = 0; mf < 4; ++mf) {
        int rowb = mt * 128 + wm * 64 + mf * 16 + (lane >> 4) * 4;
        #pragma unroll
        for (int nf = 0; nf < 4; ++nf) {
            int col = nt * 128 + wn * 64 + nf * 16 + l15;
            #pragma unroll
            for (int rr = 0; rr < 4; ++rr)
                Pp[(long)(rowb + rr) * 256 + col] = acc[mf][nf][rr];
        }
    }
}

// ---------------------------------------------------------------------------
// k_sum: y[m,o] = bias[o] + sum_sp partials[sp][m][o]; per-row (m) stats
// ---------------------------------------------------------------------------
__global__ __launch_bounds__(256) void k_sum(const float* __restrict__ partials,
                                             const float* __restrict__ bias,
                                             float* __restrict__ y,
                                             float2* __restrict__ bstats) {
    int m = blockIdx.x;
    int o = threadIdx.x;
    float acc = bias[o];
    #pragma unroll 8
    for (int spi = 0; spi < 32; ++spi)
        acc += partials[((long)spi * 1024 + m) * 256 + o];
    y[(long)m * 256 + o] = acc;

    float s = acc, s2 = acc * acc;
    #pragma unroll
    for (int off = 32; off > 0; off >>= 1) {
        s  += __shfl_down(s, off, 64);
        s2 += __shfl_down(s2, off, 64);
    }
    __shared__ float rs[4], rq[4];
    int lane = o & 63, wv = o >> 6;
    if (lane == 0) { rs[wv] = s; rq[wv] = s2; }
    __syncthreads();
    if (o == 0) {
        float2 st;
        st.x = rs[0] + rs[1] + rs[2] + rs[3];
        st.y = rq[0] + rq[1] + rq[2] + rq[3];
        bstats[m] = st;
    }
}

// ---------------------------------------------------------------------------
// k_bn: channel q = m&255: combine 4 b-row stats, normalize, write out
// ---------------------------------------------------------------------------
__global__ __launch_bounds__(256) void k_bn(const float* __restrict__ y,
                                            const float2* __restrict__ bstats,
                                            const float* __restrict__ gamma,
                                            const float* __restrict__ beta,
                                            float* __restrict__ out) {
    int m = blockIdx.x;
    int o = threadIdx.x;
    int q = m & 255;
    float2 s0 = bstats[q], s1 = bstats[256 + q], s2 = bstats[512 + q], s3 = bstats[768 + q];
    float ts = s0.x + s1.x + s2.x + s3.x;
    float tq = s0.y + s1.y + s2.y + s3.y;
    float mean = ts * (1.f / 1024.f);
    float var = tq * (1.f / 1024.f) - mean * mean;   // biased, matches ref
    float rstd = rsqrtf(var + 1e-5f);
    float v = y[(long)m * 256 + o];
    out[(long)m * 256 + o] = fmaf((v - mean) * rstd, gamma[q], beta[q]);
}

// ---------------------------------------------------------------------------
extern "C" void kernel_launch(void* const* d_in, const int* in_sizes, int n_in,
                              void* d_out, int out_size, void* d_ws, size_t ws_size,
                              hipStream_t stream) {
    const float* x     = (const float*)d_in[0];
    const float* lc_w  = (const float*)d_in[1];
    const float* w1    = (const float*)d_in[2];
    const float* bias  = (const float*)d_in[3];
    const float* gamma = (const float*)d_in[4];
    const float* beta  = (const float*)d_in[5];
    float* out = (float*)d_out;

    char* ws = (char*)d_ws;
    size_t o_T     = 0;                       // 1 MB
    size_t o_part  = o_T + 1048576;           // 33.55 MB
    size_t o_y     = o_part + 33554432;       // 1 MB
    size_t o_bst   = o_y + 1048576;           // 8 KB
    size_t o_Wbf   = o_bst + 8192;            // 32 MB
    size_t o_w1bf  = o_Wbf + 33554432;        // 128 KB

    float*          T        = (float*)(ws + o_T);
    float*          partials = (float*)(ws + o_part);
    float*          y        = (float*)(ws + o_y);
    float2*         bstats   = (float2*)(ws + o_bst);
    unsigned short* Wbf      = (unsigned short*)(ws + o_Wbf);
    unsigned short* w1bf     = (unsigned short*)(ws + o_w1bf);

    k_wcvt<<<2048, 256, 0, stream>>>(lc_w, w1, Wbf, w1bf);
    k_pre <<<256,  256, 0, stream>>>(x, T);
    k_gemm<<<512,  256, 0, stream>>>(x, Wbf, w1bf, T, partials);
    k_sum <<<1024, 256, 0, stream>>>(partials, bias, y, bstats);
    k_bn  <<<1024, 256, 0, stream>>>(y, bstats, gamma, beta, out);
}

// Round 7
// 185.319 us; speedup vs baseline: 2.1182x; 1.1050x over previous
//
#include <hip/hip_runtime.h>
#include <hip/hip_bf16.h>

typedef __attribute__((ext_vector_type(8))) short short8;
typedef __attribute__((ext_vector_type(4))) float f32x4;
typedef __attribute__((ext_vector_type(4))) unsigned int u32x4;

static __device__ __forceinline__ unsigned int cvt_pk_bf16(float lo, float hi) {
    unsigned int r;
    asm("v_cvt_pk_bf16_f32 %0, %1, %2" : "=v"(r) : "v"(lo), "v"(hi));
    return r;
}

#define GLDS(src, dst) __builtin_amdgcn_global_load_lds( \
    (const __attribute__((address_space(1))) unsigned int*)(src), \
    (__attribute__((address_space(3))) unsigned int*)(dst), 16, 0, 0)

// counted-vmcnt barrier: wait own ds ops + all-but-N vmem, then raw barrier.
// smaller N = more conservative (over-wait), never racy.
#define BARC(N) do { \
    asm volatile("s_waitcnt lgkmcnt(0) vmcnt(" #N ")" ::: "memory"); \
    __builtin_amdgcn_s_barrier(); \
    __builtin_amdgcn_sched_barrier(0); \
} while (0)

// ---------------------------------------------------------------------------
// k_prep: fused (a) swizzled bf16 convert of lc_w & w1 (validated r5/r6),
//               (b) T[b,j,k] = (j==k) ? 0 : 1/(1 - sum_q x_j^2 x_k^2)
// grid 2304 = 2048 wcvt + 256 T
// ---------------------------------------------------------------------------
__global__ __launch_bounds__(256) void k_prep(const float* __restrict__ x,
                                              const float* __restrict__ W,
                                              const float* __restrict__ w1,
                                              unsigned short* __restrict__ Wbf,
                                              unsigned short* __restrict__ w1bf,
                                              float* __restrict__ T) {
    int bid = blockIdx.x, t = threadIdx.x;
    if (bid < 2048) {
        long t0 = (long)bid * 256 + t;
        for (long u = t0; u < 2097152L; u += 524288L) {   // lc_w: 2M 8-elem units
            long i = u >> 13;
            int uu = (int)(u & 8191);
            int c = uu >> 2, cu = uu & 3;
            int s = (int)((i >> 1) & 3);
            const float* src = W + i * 65536 + c * 32 + (cu ^ s) * 8;
            f32x4 a = *(const f32x4*)src;
            f32x4 b = *(const f32x4*)(src + 4);
            u32x4 q;
            q.x = cvt_pk_bf16(a.x, a.y); q.y = cvt_pk_bf16(a.z, a.w);
            q.z = cvt_pk_bf16(b.x, b.y); q.w = cvt_pk_bf16(b.z, b.w);
            *(u32x4*)(Wbf + u * 8) = q;
        }
        if (t0 < 8192) {                   // w1: 8K units
            long u = t0;
            long i = u >> 5;
            int uu = (int)(u & 31);
            int c = uu >> 2, cu = uu & 3;
            int s = (int)((i >> 1) & 3);
            const float* src = w1 + i * 256 + c * 32 + (cu ^ s) * 8;
            f32x4 a = *(const f32x4*)src;
            f32x4 b = *(const f32x4*)(src + 4);
            u32x4 q;
            q.x = cvt_pk_bf16(a.x, a.y); q.y = cvt_pk_bf16(a.z, a.w);
            q.z = cvt_pk_bf16(b.x, b.y); q.w = cvt_pk_bf16(b.z, b.w);
            *(u32x4*)(w1bf + u * 8) = q;
        }
    } else {
        int bb = bid - 2048;               // 0..255
        int b = bb >> 6;
        int j4 = (bb & 63) * 4;
        const float* xb = x + (long)b * 65536;
        float ac0 = 0.f, ac1 = 0.f, ac2 = 0.f, ac3 = 0.f;
        #pragma unroll 8
        for (int qq = 0; qq < 256; ++qq) {
            const float* row = xb + (long)qq * 256;
            float xk = row[t];
            float xk2 = xk * xk;
            f32x4 aj = *(const f32x4*)(row + j4);
            ac0 = fmaf(aj.x * aj.x, xk2, ac0);
            ac1 = fmaf(aj.y * aj.y, xk2, ac1);
            ac2 = fmaf(aj.z * aj.z, xk2, ac2);
            ac3 = fmaf(aj.w * aj.w, xk2, ac3);
        }
        long base = (long)b * 65536 + (long)j4 * 256 + t;
        T[base +   0] = (j4     == t) ? 0.f : 1.f / (1.f - ac0);
        T[base + 256] = (j4 + 1 == t) ? 0.f : 1.f / (1.f - ac1);
        T[base + 512] = (j4 + 2 == t) ? 0.f : 1.f / (1.f - ac2);
        T[base + 768] = (j4 + 3 == t) ? 0.f : 1.f / (1.f - ac3);
    }
}

// ---------------------------------------------------------------------------
// k_gemm: r6 structure + (a) 3-buffer Bs with counted-vmcnt raw barriers,
// (b) T prefetched 2 steps ahead, (c) XOR-swizzled As (pad dropped).
// 128x128 tile, 4 waves, BK=32, grid 512 (bid = mt*64 + nt*32 + sp).
// ---------------------------------------------------------------------------
__global__ __launch_bounds__(256, 2) void k_gemm(const float* __restrict__ x,
                                                 const unsigned short* __restrict__ Wbf,
                                                 const unsigned short* __restrict__ w1bf,
                                                 const float* __restrict__ T,
                                                 float* __restrict__ partials) {
    __shared__ unsigned short As[2][128][32];   // 16 KB, XOR-swizzled cols
    __shared__ unsigned short Bs[3][128][32];   // 24 KB, linear (gload_lds dest)

    const int bid = blockIdx.x;
    const int mt = bid >> 6;            // 0..7
    const int nt = (bid >> 5) & 1;      // 0..1
    const int sp = bid & 31;            // 0..31
    const int tid = threadIdx.x;
    const int lane = tid & 63;
    const int l15 = lane & 15;
    const int cu = lane >> 4;
    const int xu = cu ^ ((l15 >> 1) & 3);   // swizzled read unit (As and Bs)
    const int wid = tid >> 6;
    const int wm = wid >> 1, wn = wid & 1;
    const int b = mt >> 1;

    // A staging role: one row, 16 cols per thread
    const int r = tid >> 1;
    const int ch = (tid & 1) * 16;
    const int u0 = ch >> 3;                 // 0 or 2
    const int sAr = (r >> 1) & 3;           // write-side swizzle for row r
    const int wcol0 = ((u0 ^ sAr) * 8);
    const int wcol1 = (((u0 + 1) ^ sAr) * 8);

    const float* xrow = x + (long)(mt * 128 + r) * 256;
    const float* Trow = T + (long)b * 65536 + (long)(sp * 8) * 256 + ch;

    // B staging: wave wid covers rows wid*32..+32 (2 gload_lds, 16 rows each)
    const unsigned short* Bsrc0 = Wbf + (long)(nt * 128 + wid * 32 + (lane >> 2)) * 65536
                                      + (long)sp * 2048 + (lane & 3) * 8;
    const unsigned short* Bsrc1 = Bsrc0 + 16L * 65536;

    // the 8 j-values of this chunk for this thread's A row
    f32x4 xjA = *(const f32x4*)(xrow + sp * 8);
    f32x4 xjB = *(const f32x4*)(xrow + sp * 8 + 4);
    const float xj8[8] = {xjA.x, xjA.y, xjA.z, xjA.w, xjB.x, xjB.y, xjB.z, xjB.w};

    f32x4 acc[4][4];
    #pragma unroll
    for (int a = 0; a < 4; ++a)
        #pragma unroll
        for (int c = 0; c < 4; ++c) acc[a][c] = (f32x4){0.f, 0.f, 0.f, 0.f};

    f32x4 xw0, xw1, xw2, xw3;     // x window, current kw
    f32x4 tn0, tn1, tn2, tn3;     // T for step s+1 (loaded at s-1)
    unsigned short* const As0 = &As[0][0][0];
    unsigned short* const Bs0 = &Bs[0][0][0];

    // ---- prologue: G(0)->buf0, G(1)->buf1, T(0)+T(1), x(kw0), A(0)->As[0] ----
    {
        GLDS(Bsrc0, Bs0 + (long)(wid * 32) * 32);
        GLDS(Bsrc1, Bs0 + (long)(wid * 32 + 16) * 32);
        GLDS(Bsrc0 + 256, Bs0 + 4096 + (long)(wid * 32) * 32);        // T(1): kt=1 -> off 256
        GLDS(Bsrc1 + 256, Bs0 + 4096 + (long)(wid * 32 + 16) * 32);
        xw0 = *(const f32x4*)(xrow + ch + 0);
        xw1 = *(const f32x4*)(xrow + ch + 4);
        xw2 = *(const f32x4*)(xrow + ch + 8);
        xw3 = *(const f32x4*)(xrow + ch + 12);
        f32x4 t0 = *(const f32x4*)(Trow + 0);
        f32x4 t1 = *(const f32x4*)(Trow + 4);
        f32x4 t2 = *(const f32x4*)(Trow + 8);
        f32x4 t3 = *(const f32x4*)(Trow + 12);
        tn0 = *(const f32x4*)(Trow + 256 + 0);     // T(1)
        tn1 = *(const f32x4*)(Trow + 256 + 4);
        tn2 = *(const f32x4*)(Trow + 256 + 8);
        tn3 = *(const f32x4*)(Trow + 256 + 12);
        const float xj = xj8[0];
        u32x4 qa, qb;
        qa.x = cvt_pk_bf16(xj * xw0.x * t0.x, xj * xw0.y * t0.y);
        qa.y = cvt_pk_bf16(xj * xw0.z * t0.z, xj * xw0.w * t0.w);
        qa.z = cvt_pk_bf16(xj * xw1.x * t1.x, xj * xw1.y * t1.y);
        qa.w = cvt_pk_bf16(xj * xw1.z * t1.z, xj * xw1.w * t1.w);
        qb.x = cvt_pk_bf16(xj * xw2.x * t2.x, xj * xw2.y * t2.y);
        qb.y = cvt_pk_bf16(xj * xw2.z * t2.z, xj * xw2.w * t2.w);
        qb.z = cvt_pk_bf16(xj * xw3.x * t3.x, xj * xw3.y * t3.y);
        qb.w = cvt_pk_bf16(xj * xw3.z * t3.z, xj * xw3.w * t3.w);
        *(u32x4*)(As0 + (long)r * 32 + wcol0) = qa;
        *(u32x4*)(As0 + (long)r * 32 + wcol1) = qb;
    }
    __syncthreads();   // full drain once: Bs0, Bs1, As[0], T regs all ready

    int b0 = 0;   // (2*kw)%3
    #pragma unroll 1
    for (int kw = 0; kw < 8; ++kw) {
        f32x4 nx0, nx1, nx2, nx3;   // next-kw x, loaded at jj==6
        #pragma unroll
        for (int jj = 0; jj < 8; ++jj) {
            // buffer indices (jj compile-time, b0 runtime 0..2)
            int rb = b0 + (jj % 3); rb = rb >= 3 ? rb - 3 : rb;       // read buf (s%3)
            int wb = rb + 2; wb = wb >= 3 ? wb - 3 : wb;              // write buf (s+2)%3
            const int cbuf = jj & 1;         // As read
            const int nbuf = cbuf ^ 1;       // As write

            // ---- 1. issue gloads for step s+2 + T(s+2) register prefetch ----
            const int nkw2 = kw + ((jj + 2) >> 3);
            const long off2 = (long)((jj + 2) & 7) * 256 + (long)nkw2 * 32;
            GLDS(Bsrc0 + off2, Bs0 + (long)wb * 4096 + (long)(wid * 32) * 32);
            GLDS(Bsrc1 + off2, Bs0 + (long)wb * 4096 + (long)(wid * 32 + 16) * 32);
            f32x4 tf0 = *(const f32x4*)(Trow + off2 + 0);
            f32x4 tf1 = *(const f32x4*)(Trow + off2 + 4);
            f32x4 tf2 = *(const f32x4*)(Trow + off2 + 8);
            f32x4 tf3 = *(const f32x4*)(Trow + off2 + 12);
            if (jj == 6) {                   // x for kw+1 (clamped at kw==7; unused)
                const long xo = (kw == 7) ? 0 : (long)(kw + 1) * 32;
                nx0 = *(const f32x4*)(xrow + xo + ch + 0);
                nx1 = *(const f32x4*)(xrow + xo + ch + 4);
                nx2 = *(const f32x4*)(xrow + xo + ch + 8);
                nx3 = *(const f32x4*)(xrow + xo + ch + 12);
            }

            // ---- 2. fragments (both XOR-swizzled reads) ----
            short8 af[4], bfv[4];
            #pragma unroll
            for (int mf = 0; mf < 4; ++mf)
                af[mf] = *(const short8*)(As0 + (long)cbuf * 4096
                            + (long)(wm * 64 + mf * 16 + l15) * 32 + xu * 8);
            #pragma unroll
            for (int nf = 0; nf < 4; ++nf)
                bfv[nf] = *(const short8*)(Bs0 + (long)rb * 4096
                            + (long)(wn * 64 + nf * 16 + l15) * 32 + xu * 8);

            // ---- 3. A-gen for step s+1 (T from regs loaded at s-1) ----
            {
                const float xjn = xj8[(jj + 1) & 7];
                const f32x4 w0 = (jj == 7) ? nx0 : xw0;
                const f32x4 w1v = (jj == 7) ? nx1 : xw1;
                const f32x4 w2 = (jj == 7) ? nx2 : xw2;
                const f32x4 w3 = (jj == 7) ? nx3 : xw3;
                u32x4 qa, qb;
                qa.x = cvt_pk_bf16(xjn * w0.x * tn0.x, xjn * w0.y * tn0.y);
                qa.y = cvt_pk_bf16(xjn * w0.z * tn0.z, xjn * w0.w * tn0.w);
                qa.z = cvt_pk_bf16(xjn * w1v.x * tn1.x, xjn * w1v.y * tn1.y);
                qa.w = cvt_pk_bf16(xjn * w1v.z * tn1.z, xjn * w1v.w * tn1.w);
                qb.x = cvt_pk_bf16(xjn * w2.x * tn2.x, xjn * w2.y * tn2.y);
                qb.y = cvt_pk_bf16(xjn * w2.z * tn2.z, xjn * w2.w * tn2.w);
                qb.z = cvt_pk_bf16(xjn * w3.x * tn3.x, xjn * w3.y * tn3.y);
                qb.w = cvt_pk_bf16(xjn * w3.z * tn3.z, xjn * w3.w * tn3.w);
                *(u32x4*)(As0 + (long)nbuf * 4096 + (long)r * 32 + wcol0) = qa;
                *(u32x4*)(As0 + (long)nbuf * 4096 + (long)r * 32 + wcol1) = qb;
            }

            // ---- 4. MFMA ----
            #pragma unroll
            for (int mf = 0; mf < 4; ++mf)
                #pragma unroll
                for (int nf = 0; nf < 4; ++nf)
                    acc[mf][nf] = __builtin_amdgcn_mfma_f32_16x16x32_bf16(
                        af[mf], bfv[nf], acc[mf][nf], 0, 0, 0);

            // ---- 5. rotate prefetch regs ----
            tn0 = tf0; tn1 = tf1; tn2 = tf2; tn3 = tf3;
            if (jj == 7) { xw0 = nx0; xw1 = nx1; xw2 = nx2; xw3 = nx3; }

            // ---- 6. counted-vmcnt barrier (needs G(s-1) retired; true bound
            //         is 10/14 with margin 2 for safety — smaller N never races)
            if (jj == 6 || jj == 7) { BARC(12); } else { BARC(8); }
        }
        b0 += 2; if (b0 >= 3) b0 -= 3;
    }

    // ---- base-linear fold: sp<8 blocks do one extra K-step over w1 ----
    __syncthreads();   // drain trailing garbage prefetches before Bs reuse
    if (sp < 8) {
        const unsigned short* W1s = w1bf + (long)(nt * 128 + wid * 32 + (lane >> 2)) * 256
                                        + sp * 32 + (lane & 3) * 8;
        GLDS(W1s, Bs0 + (long)(wid * 32) * 32);
        GLDS(W1s + 16L * 256, Bs0 + (long)(wid * 32 + 16) * 32);
        f32x4 a0 = *(const f32x4*)(xrow + sp * 32 + ch + 0);
        f32x4 a1 = *(const f32x4*)(xrow + sp * 32 + ch + 4);
        f32x4 a2 = *(const f32x4*)(xrow + sp * 32 + ch + 8);
        f32x4 a3 = *(const f32x4*)(xrow + sp * 32 + ch + 12);
        u32x4 qa, qb;
        qa.x = cvt_pk_bf16(a0.x, a0.y); qa.y = cvt_pk_bf16(a0.z, a0.w);
        qa.z = cvt_pk_bf16(a1.x, a1.y); qa.w = cvt_pk_bf16(a1.z, a1.w);
        qb.x = cvt_pk_bf16(a2.x, a2.y); qb.y = cvt_pk_bf16(a2.z, a2.w);
        qb.z = cvt_pk_bf16(a3.x, a3.y); qb.w = cvt_pk_bf16(a3.z, a3.w);
        *(u32x4*)(As0 + (long)r * 32 + wcol0) = qa;
        *(u32x4*)(As0 + (long)r * 32 + wcol1) = qb;
        __syncthreads();
        short8 af[4], bfv[4];
        #pragma unroll
        for (int mf = 0; mf < 4; ++mf)
            af[mf] = *(const short8*)(As0 + (long)(wm * 64 + mf * 16 + l15) * 32 + xu * 8);
        #pragma unroll
        for (int nf = 0; nf < 4; ++nf)
            bfv[nf] = *(const short8*)(Bs0 + (long)(wn * 64 + nf * 16 + l15) * 32 + xu * 8);
        #pragma unroll
        for (int mf = 0; mf < 4; ++mf)
            #pragma unroll
            for (int nf = 0; nf < 4; ++nf)
                acc[mf][nf] = __builtin_amdgcn_mfma_f32_16x16x32_bf16(
                    af[mf], bfv[nf], acc[mf][nf], 0, 0, 0);
    }

    // epilogue: C/D layout col = lane&15, row = (lane>>4)*4 + reg
    float* Pp = partials + (long)sp * 262144;
    #pragma unroll
    for (int mf = 0; mf < 4; ++mf) {
        int rowb = mt * 128 + wm * 64 + mf * 16 + (lane >> 4) * 4;
        #pragma unroll
        for (int nf = 0; nf < 4; ++nf) {
            int col = nt * 128 + wn * 64 + nf * 16 + l15;
            #pragma unroll
            for (int rr = 0; rr < 4; ++rr)
                Pp[(long)(rowb + rr) * 256 + col] = acc[mf][nf][rr];
        }
    }
}

// ---------------------------------------------------------------------------
// k_sum: y[m,o] = bias[o] + sum_sp partials[sp][m][o]; per-row (m) stats
// ---------------------------------------------------------------------------
__global__ __launch_bounds__(256) void k_sum(const float* __restrict__ partials,
                                             const float* __restrict__ bias,
                                             float* __restrict__ y,
                                             float2* __restrict__ bstats) {
    int m = blockIdx.x;
    int o = threadIdx.x;
    float acc = bias[o];
    #pragma unroll 8
    for (int spi = 0; spi < 32; ++spi)
        acc += partials[((long)spi * 1024 + m) * 256 + o];
    y[(long)m * 256 + o] = acc;

    float s = acc, s2 = acc * acc;
    #pragma unroll
    for (int off = 32; off > 0; off >>= 1) {
        s  += __shfl_down(s, off, 64);
        s2 += __shfl_down(s2, off, 64);
    }
    __shared__ float rs[4], rq[4];
    int lane = o & 63, wv = o >> 6;
    if (lane == 0) { rs[wv] = s; rq[wv] = s2; }
    __syncthreads();
    if (o == 0) {
        float2 st;
        st.x = rs[0] + rs[1] + rs[2] + rs[3];
        st.y = rq[0] + rq[1] + rq[2] + rq[3];
        bstats[m] = st;
    }
}

// ---------------------------------------------------------------------------
// k_bn: channel q = m&255: combine 4 b-row stats, normalize, write out
// ---------------------------------------------------------------------------
__global__ __launch_bounds__(256) void k_bn(const float* __restrict__ y,
                                            const float2* __restrict__ bstats,
                                            const float* __restrict__ gamma,
                                            const float* __restrict__ beta,
                                            float* __restrict__ out) {
    int m = blockIdx.x;
    int o = threadIdx.x;
    int q = m & 255;
    float2 s0 = bstats[q], s1 = bstats[256 + q], s2 = bstats[512 + q], s3 = bstats[768 + q];
    float ts = s0.x + s1.x + s2.x + s3.x;
    float tq = s0.y + s1.y + s2.y + s3.y;
    float mean = ts * (1.f / 1024.f);
    float var = tq * (1.f / 1024.f) - mean * mean;   // biased, matches ref
    float rstd = rsqrtf(var + 1e-5f);
    float v = y[(long)m * 256 + o];
    out[(long)m * 256 + o] = fmaf((v - mean) * rstd, gamma[q], beta[q]);
}

// ---------------------------------------------------------------------------
extern "C" void kernel_launch(void* const* d_in, const int* in_sizes, int n_in,
                              void* d_out, int out_size, void* d_ws, size_t ws_size,
                              hipStream_t stream) {
    const float* x     = (const float*)d_in[0];
    const float* lc_w  = (const float*)d_in[1];
    const float* w1    = (const float*)d_in[2];
    const float* bias  = (const float*)d_in[3];
    const float* gamma = (const float*)d_in[4];
    const float* beta  = (const float*)d_in[5];
    float* out = (float*)d_out;

    char* ws = (char*)d_ws;
    size_t o_T     = 0;                       // 1 MB
    size_t o_part  = o_T + 1048576;           // 33.55 MB
    size_t o_y     = o_part + 33554432;       // 1 MB
    size_t o_bst   = o_y + 1048576;           // 8 KB
    size_t o_Wbf   = o_bst + 8192;            // 32 MB
    size_t o_w1bf  = o_Wbf + 33554432;        // 128 KB

    float*          T        = (float*)(ws + o_T);
    float*          partials = (float*)(ws + o_part);
    float*          y        = (float*)(ws + o_y);
    float2*         bstats   = (float2*)(ws + o_bst);
    unsigned short* Wbf      = (unsigned short*)(ws + o_Wbf);
    unsigned short* w1bf     = (unsigned short*)(ws + o_w1bf);

    k_prep<<<2304, 256, 0, stream>>>(x, lc_w, w1, Wbf, w1bf, T);
    k_gemm<<<512,  256, 0, stream>>>(x, Wbf, w1bf, T, partials);
    k_sum <<<1024, 256, 0, stream>>>(partials, bias, y, bstats);
    k_bn  <<<1024, 256, 0, stream>>>(y, bstats, gamma, beta, out);
}